// Round 6
// baseline (363.136 us; speedup 1.0000x reference)
//
#include <hip/hip_runtime.h>
#include <hip/hip_bf16.h>

// MultiHeadAttn: out = LN(h + Attn(h) @ Wo)
// Round 5 recovery: exact round-2 kernels (last fully-validated state) +
// fused QKV projection GEMM only (dataflow validated by r4 launch-1).
// No setprio, no inline-asm fences, round-2 defer-max softmax verbatim.

typedef __attribute__((ext_vector_type(4))) float f32x4;
typedef __attribute__((ext_vector_type(16))) float f32x16;
typedef __attribute__((ext_vector_type(8))) short s16x8;
typedef unsigned short u16;
typedef unsigned int u32;
typedef __attribute__((ext_vector_type(4))) u16 u16x4;
typedef __attribute__((ext_vector_type(2))) u32 u32x2;

#define SEQ   2048
#define BATCH 4
#define NH    16
#define DH    64
#define DM    1024
#define ROWS  (SEQ*BATCH)   // 8192

// 0.125 (1/sqrt(64)) * log2(e): scores land in log2 domain -> exp2 = 1 VALU op
#define QSCALE 0.18033688011112042f
#define DEFER_THR 11.5416f   // 8 nats in log2 units

__device__ inline u16 f2bf(float x) {
    u32 u = __float_as_uint(x);
    u += 0x7FFF + ((u >> 16) & 1);   // round-to-nearest-even
    return (u16)(u >> 16);
}

__device__ inline u32 cvtpk_bf16(float lo, float hi_) {
    u32 r;
    asm("v_cvt_pk_bf16_f32 %0, %1, %2" : "=v"(r) : "v"(lo), "v"(hi_));
    return r;
}

__device__ inline void gload16(const void* g, void* l) {
    __builtin_amdgcn_global_load_lds((const __attribute__((address_space(1))) void*)g,
                                     (__attribute__((address_space(3))) void*)l, 16, 0, 0);
}

// ---------------- elementwise fp32 -> bf16 ----------------
__global__ __launch_bounds__(256) void conv_f32_bf16(const float* __restrict__ src,
                                                     u16* __restrict__ dst, int n4) {
    int idx = blockIdx.x * 256 + threadIdx.x;
    if (idx >= n4) return;
    f32x4 v = ((const f32x4*)src)[idx];
    u16x4 o;
    #pragma unroll
    for (int j = 0; j < 4; ++j) o[j] = f2bf(v[j]);
    ((u16x4*)dst)[idx] = o;
}

// ---------------- transpose + convert: W [K][N] fp32 -> WT [N][K] bf16 ----------------
__global__ __launch_bounds__(1024) void transconv_k(const float* __restrict__ src,
                                                    u16* __restrict__ dst, int K, int N) {
    __shared__ float t[32][33];
    int tx = threadIdx.x, ty = threadIdx.y;
    int nt = blockIdx.x * 32, kt = blockIdx.y * 32;
    t[ty][tx] = src[(size_t)(kt + ty) * N + nt + tx];
    __syncthreads();
    dst[(size_t)(nt + ty) * K + kt + tx] = f2bf(t[tx][ty]);
}

// ---------------- GEMM: C[M][N] = A[M][K=1024] * BT[N][K]^T ----------------
// round-2 structure: 128x128 tile, BK=32, double-buffered LDS via global_load_lds,
// source-swizzled (rule #21), plain __syncthreads only.
// MODE 0 (QKV fused, N=3072): col<1024 -> q (scaled); <2048 -> k; else v
// MODE 2: out fp32 = acc + h (residual)
template<int MODE>
__global__ __launch_bounds__(256) void gemm_k(const u16* __restrict__ A,
                                              const u16* __restrict__ BT,
                                              const float* __restrict__ hres,
                                              u16* __restrict__ o_q,
                                              u16* __restrict__ o_k,
                                              u16* __restrict__ o_v,
                                              float* __restrict__ o_f) {
    __shared__ u16 Al[2][128 * 32];
    __shared__ u16 Bl[2][128 * 32];
    int lane = threadIdx.x & 63, wid = threadIdx.x >> 6;
    int lr = lane & 15, lg = lane >> 4;      // lg in 0..3
    int m0 = blockIdx.x * 128, n0 = blockIdx.y * 128;
    int wr = wid >> 1, wc = wid & 1;

    f32x4 acc[4][4];
    #pragma unroll
    for (int mi = 0; mi < 4; ++mi)
        #pragma unroll
        for (int ni = 0; ni < 4; ++ni)
            #pragma unroll
            for (int rr = 0; rr < 4; ++rr) acc[mi][ni][rr] = 0.f;

#define GEMM_STAGE(bb, kt) do {                                                    \
    int kk = (kt) * 32;                                                            \
    _Pragma("unroll")                                                              \
    for (int it = 0; it < 2; ++it) {                                               \
        int c = (int)threadIdx.x + it * 256;                                       \
        int row = c >> 2, sub = c & 3;                                             \
        int sc = (sub ^ (row & 3)) * 8;                                            \
        gload16(A  + (size_t)(m0 + row) * 1024 + kk + sc,                          \
                &Al[bb][(wid * 64 + it * 256) * 8]);                               \
        gload16(BT + (size_t)(n0 + row) * 1024 + kk + sc,                          \
                &Bl[bb][(wid * 64 + it * 256) * 8]);                               \
    } } while (0)

    GEMM_STAGE(0, 0);
    __syncthreads();
    int cur = 0;
    for (int kt = 0; kt < 32; ++kt) {
        if (kt + 1 < 32) GEMM_STAGE(cur ^ 1, kt + 1);
        const u16* Ab = &Al[cur][0];
        const u16* Bb = &Bl[cur][0];
        s16x8 af[4], bf[4];
        #pragma unroll
        for (int mi = 0; mi < 4; ++mi) {
            int row = wr * 64 + mi * 16 + lr;
            af[mi] = *(const s16x8*)(Ab + row * 32 + ((lg ^ (row & 3)) * 8));
        }
        #pragma unroll
        for (int ni = 0; ni < 4; ++ni) {
            int row = wc * 64 + ni * 16 + lr;
            bf[ni] = *(const s16x8*)(Bb + row * 32 + ((lg ^ (row & 3)) * 8));
        }
        #pragma unroll
        for (int mi = 0; mi < 4; ++mi)
            #pragma unroll
            for (int ni = 0; ni < 4; ++ni)
                acc[mi][ni] = __builtin_amdgcn_mfma_f32_16x16x32_bf16(af[mi], bf[ni], acc[mi][ni], 0, 0, 0);
        __syncthreads();
        cur ^= 1;
    }
#undef GEMM_STAGE

    #pragma unroll
    for (int mi = 0; mi < 4; ++mi)
        #pragma unroll
        for (int rr = 0; rr < 4; ++rr) {
            int row = m0 + wr * 64 + mi * 16 + lg * 4 + rr;   // row = i*4 + b
            int ib = row >> 2, bb = row & 3;
            #pragma unroll
            for (int ni = 0; ni < 4; ++ni) {
                int col = n0 + wc * 64 + ni * 16 + lr;
                float v = acc[mi][ni][rr];
                if (MODE == 0) {
                    if (col < 1024) {
                        int nn = col >> 6, dd = col & 63;
                        o_q[(((size_t)(bb * 16 + nn) * SEQ + ib) << 6) + dd] = f2bf(v * QSCALE);
                    } else if (col < 2048) {
                        int c2 = col - 1024, nn = c2 >> 6, dd = c2 & 63;
                        o_k[(((size_t)(bb * 16 + nn) * SEQ + ib) << 6) + dd] = f2bf(v);
                    } else {
                        int c2 = col - 2048, nn = c2 >> 6, dd = c2 & 63;
                        o_v[(((size_t)(bb * 16 + nn) * SEQ + ib) << 6) + dd] = f2bf(v);
                    }
                } else {
                    size_t off = (size_t)row * 1024 + col;
                    o_f[off] = v + hres[off];
                }
            }
        }
}

// ---------------- V transpose per (b,n): v_nat [p][j][d] -> vT [p][d][j] ----------------
__global__ __launch_bounds__(256) void vtrans_k(const u16* __restrict__ vn, u16* __restrict__ vT) {
    __shared__ u16 t[64][65];
    int p = blockIdx.y, j0 = blockIdx.x * 64;
    const u16* src = vn + ((size_t)p * SEQ + j0) * 64;
    #pragma unroll
    for (int it = 0; it < 2; ++it) {
        int idx = threadIdx.x + it * 256;
        int row = idx >> 3, ch = idx & 7;
        s16x8 v = *(const s16x8*)(src + (size_t)row * 64 + ch * 8);
        #pragma unroll
        for (int jj = 0; jj < 8; ++jj) t[row][ch * 8 + jj] = (u16)v[jj];
    }
    __syncthreads();
    u16* dst = vT + (size_t)p * 64 * SEQ + j0;
    #pragma unroll
    for (int it = 0; it < 2; ++it) {
        int idx = threadIdx.x + it * 256;
        int d = idx >> 3, ch = idx & 7;
        s16x8 o;
        #pragma unroll
        for (int jj = 0; jj < 8; ++jj) o[jj] = (short)t[ch * 8 + jj][d];
        *(s16x8*)(dst + (size_t)d * SEQ + ch * 8) = o;
    }
}

// ---------------- flash attention, LDS-staged K/V, swapped-operand 32x32x16 ----------------
// round-2 kernel verbatim. grid 1024 x 256; 4 waves/block, 32 q-rows/wave.
__global__ __launch_bounds__(256) void attn_k(const u16* __restrict__ qw, const u16* __restrict__ kw,
                                              const u16* __restrict__ vT, u16* __restrict__ avw) {
    __shared__ u16 Kl[2][64 * 64];
    __shared__ u16 Vl[2][64 * 64];
    int lane = threadIdx.x & 63, wid = threadIdx.x >> 6;
    int l31 = lane & 31, hi = lane >> 5;
    int f = blockIdx.x;
    int pair = (f & 7) * 8 + ((f >> 3) & 7);   // bijective; one pair's 16 blocks -> one XCD
    int qt = f >> 6;
    int b = pair >> 4, n = pair & 15;
    int q0 = qt * 128 + wid * 32;

    const u16* Q  = qw + ((size_t)pair * SEQ + q0) * 64;
    const u16* Kg = kw + (size_t)pair * SEQ * 64;
    const u16* Vg = vT + (size_t)pair * 64 * SEQ;

    // Q B-fragments (held all kernel); qw already scaled by QSCALE (log2 domain)
    s16x8 qf[4];
    #pragma unroll
    for (int kt = 0; kt < 4; ++kt)
        qf[kt] = *(const s16x8*)(Q + (size_t)l31 * 64 + kt * 16 + hi * 8);

    f32x16 Ot[2];   // O^T accum: d = (reg&3)+8*(reg>>2)+4*hi+32*dt, q = l31
    #pragma unroll
    for (int dt = 0; dt < 2; ++dt)
        #pragma unroll
        for (int r = 0; r < 16; ++r) Ot[dt][r] = 0.f;
    float m = -3.0e38f, lsum = 0.f;

#define ATTN_STAGE(bb, j0s) do {                                                   \
    _Pragma("unroll")                                                              \
    for (int it = 0; it < 2; ++it) {                                               \
        int c = (int)threadIdx.x + it * 256;                                       \
        int row = c >> 3, cl = c & 7;                                              \
        int sc = (cl ^ (row & 7)) * 8;                                             \
        gload16(Kg + (size_t)((j0s) + row) * 64 + sc,                              \
                &Kl[bb][(wid * 64 + it * 256) * 8]);                               \
        gload16(Vg + (size_t)row * SEQ + (j0s) + sc,                               \
                &Vl[bb][(wid * 64 + it * 256) * 8]);                               \
    } } while (0)

    ATTN_STAGE(0, 0);
    __syncthreads();
    int cur = 0;

    for (int jt = 0; jt < 32; ++jt) {
        int j0 = jt * 64;
        if (jt + 1 < 32) ATTN_STAGE(cur ^ 1, j0 + 64);
        const u16* Kb = &Kl[cur][0];
        const u16* Vb = &Vl[cur][0];

        // ---- S^T = K Q^T : two 32x32 tiles ----
        f32x16 s0, s1;
        #pragma unroll
        for (int r = 0; r < 16; ++r) { s0[r] = 0.f; s1[r] = 0.f; }
        #pragma unroll
        for (int kt = 0; kt < 4; ++kt) {
            int cg = kt * 2 + hi;
            int r0 = l31;
            s16x8 ka = *(const s16x8*)(Kb + r0 * 64 + ((cg ^ (r0 & 7)) * 8));
            s0 = __builtin_amdgcn_mfma_f32_32x32x16_bf16(ka, qf[kt], s0, 0, 0, 0);
        }
        #pragma unroll
        for (int kt = 0; kt < 4; ++kt) {
            int cg = kt * 2 + hi;
            int r1 = 32 + l31;
            s16x8 ka = *(const s16x8*)(Kb + r1 * 64 + ((cg ^ (r1 & 7)) * 8));
            s1 = __builtin_amdgcn_mfma_f32_32x32x16_bf16(ka, qf[kt], s1, 0, 0, 0);
        }

        // ---- lane-local max over 32 scores ----
        float mx[16];
        #pragma unroll
        for (int r = 0; r < 16; ++r) mx[r] = fmaxf(s0[r], s1[r]);
        #pragma unroll
        for (int st = 8; st >= 1; st >>= 1)
            #pragma unroll
            for (int r = 0; r < st; ++r) mx[r] = fmaxf(mx[r], mx[r + st]);
        float pmax = mx[0];

        // ---- defer-max (T13, log2 units) ----
        if (!__all(pmax - m <= DEFER_THR)) {
            float pmo = fmaxf(pmax, __shfl_xor(pmax, 32, 64));
            float mn = fmaxf(m, pmo);
            float sf = __builtin_amdgcn_exp2f(m - mn);
            m = mn;
            lsum *= sf;
            #pragma unroll
            for (int dt = 0; dt < 2; ++dt)
                #pragma unroll
                for (int r = 0; r < 16; ++r) Ot[dt][r] *= sf;
        }

        // ---- p = exp2(s - m); fp32 sum (4 partials); pack via v_cvt_pk_bf16_f32 ----
        u32 pk[16];
        float ps[4] = {0.f, 0.f, 0.f, 0.f};
        #pragma unroll
        for (int mp = 0; mp < 8; ++mp) {
            float a0 = __builtin_amdgcn_exp2f(s0[2 * mp] - m);
            float a1 = __builtin_amdgcn_exp2f(s0[2 * mp + 1] - m);
            ps[mp & 3] += a0 + a1;
            pk[mp] = cvtpk_bf16(a0, a1);
            float b0 = __builtin_amdgcn_exp2f(s1[2 * mp] - m);
            float b1 = __builtin_amdgcn_exp2f(s1[2 * mp + 1] - m);
            ps[(mp & 3) ^ 2] += b0 + b1;
            pk[8 + mp] = cvtpk_bf16(b0, b1);
        }
        lsum += (ps[0] + ps[1]) + (ps[2] + ps[3]);

        // ---- O^T += V^T P^T ; fragment built by permlane32_swap (2 per 16-slice) ----
        #pragma unroll
        for (int t = 0; t < 2; ++t)
            #pragma unroll
            for (int kt2 = 0; kt2 < 2; ++kt2) {
                int base = t * 8 + kt2 * 4;
                u32x2 w02 = __builtin_amdgcn_permlane32_swap(pk[base + 0], pk[base + 2], false, false);
                u32x2 w13 = __builtin_amdgcn_permlane32_swap(pk[base + 1], pk[base + 3], false, false);
                union { u32 w[4]; s16x8 v; } fr;
                fr.w[0] = w02[0]; fr.w[1] = w13[0]; fr.w[2] = w02[1]; fr.w[3] = w13[1];
                #pragma unroll
                for (int dt = 0; dt < 2; ++dt) {
                    int rv = dt * 32 + l31;
                    int cgv = t * 4 + kt2 * 2 + hi;
                    s16x8 va = *(const s16x8*)(Vb + rv * 64 + ((cgv ^ (rv & 7)) * 8));
                    Ot[dt] = __builtin_amdgcn_mfma_f32_32x32x16_bf16(va, fr.v, Ot[dt], 0, 0, 0);
                }
            }
        __syncthreads();
        cur ^= 1;
    }
#undef ATTN_STAGE

    // ---- epilogue: av[(i*4+b)][n*64+d] = O^T[d][q] / L ----
    float L = lsum + __shfl_xor(lsum, 32, 64);
    float inv = 1.f / L;
    int i = q0 + l31;
    size_t rowo = (size_t)(i * 4 + b) * 1024 + n * 64;
    #pragma unroll
    for (int dt = 0; dt < 2; ++dt)
        #pragma unroll
        for (int rq = 0; rq < 4; ++rq) {
            int dbase = dt * 32 + rq * 8 + hi * 4;
            u16x4 o;
            #pragma unroll
            for (int e = 0; e < 4; ++e) o[e] = f2bf(Ot[dt][rq * 4 + e] * inv);
            *(u16x4*)(avw + rowo + dbase) = o;
        }
}

// ---------------- in-place layernorm over rows of 1024 fp32 ----------------
__global__ __launch_bounds__(256) void ln_k(float* __restrict__ y,
                                            const float* __restrict__ g,
                                            const float* __restrict__ be) {
    int row = blockIdx.x, t = threadIdx.x;
    f32x4 v = ((const f32x4*)(y + (size_t)row * 1024))[t];
    float s = v[0] + v[1] + v[2] + v[3];
    float q = v[0] * v[0] + v[1] * v[1] + v[2] * v[2] + v[3] * v[3];
    #pragma unroll
    for (int msk = 1; msk < 64; msk <<= 1) {
        s += __shfl_xor(s, msk, 64);
        q += __shfl_xor(q, msk, 64);
    }
    __shared__ float ss[4], qq[4];
    int w = t >> 6;
    if ((t & 63) == 0) { ss[w] = s; qq[w] = q; }
    __syncthreads();
    s = ss[0] + ss[1] + ss[2] + ss[3];
    q = qq[0] + qq[1] + qq[2] + qq[3];
    float mean = s * (1.f / 1024.f);
    float var = q * (1.f / 1024.f) - mean * mean;
    float rstd = rsqrtf(var + 1e-5f);
    f32x4 gv = ((const f32x4*)g)[t];
    f32x4 bv = ((const f32x4*)be)[t];
    f32x4 o;
    #pragma unroll
    for (int j = 0; j < 4; ++j) o[j] = (v[j] - mean) * rstd * gv[j] + bv[j];
    ((f32x4*)(y + (size_t)row * 1024))[t] = o;
}

extern "C" void kernel_launch(void* const* d_in, const int* in_sizes, int n_in,
                              void* d_out, int out_size, void* d_ws, size_t ws_size,
                              hipStream_t stream) {
    const float* h     = (const float*)d_in[0];
    const float* Wq    = (const float*)d_in[1];
    const float* Wkv   = (const float*)d_in[2];
    const float* Wo    = (const float*)d_in[3];
    const float* gamma = (const float*)d_in[4];
    const float* beta  = (const float*)d_in[5];
    float* out = (float*)d_out;

    char* w = (char*)d_ws;
    u16* hb   = (u16*)w; w += (size_t)ROWS * DM * 2;        // 16 MB
    u16* WqT  = (u16*)w; w += (size_t)DM * DM * 2;          //  2 MB (WkvT contiguous after)
    u16* WkvT = (u16*)w; w += (size_t)2 * DM * DM * 2;      //  4 MB
    u16* WoT  = (u16*)w; w += (size_t)DM * DM * 2;          //  2 MB
    u16* qw   = (u16*)w; w += (size_t)64 * SEQ * 64 * 2;    // 16 MB
    u16* kw   = (u16*)w; w += (size_t)64 * SEQ * 64 * 2;    // 16 MB
    u16* vn   = (u16*)w; w += (size_t)64 * SEQ * 64 * 2;    // 16 MB
    u16* vT   = (u16*)w; w += (size_t)64 * SEQ * 64 * 2;    // 16 MB
    u16* avw  = vn;   // reuse: vn dead after vtrans_k

    conv_f32_bf16<<<ROWS * DM / 4 / 256, 256, 0, stream>>>(h, hb, ROWS * DM / 4);
    dim3 b32(32, 32);
    transconv_k<<<dim3(32, 32), b32, 0, stream>>>(Wq, WqT, 1024, 1024);
    transconv_k<<<dim3(64, 32), b32, 0, stream>>>(Wkv, WkvT, 1024, 2048);
    transconv_k<<<dim3(32, 32), b32, 0, stream>>>(Wo, WoT, 1024, 1024);

    // fused QKV projection: BT = [WqT ; WkvT] rows 0..3071
    gemm_k<0><<<dim3(64, 24), 256, 0, stream>>>(hb, WqT, nullptr, qw, kw, vn, nullptr);
    vtrans_k<<<dim3(32, 64), 256, 0, stream>>>(vn, vT);
    attn_k<<<1024, 256, 0, stream>>>(qw, kw, vT, avw);
    gemm_k<2><<<dim3(64, 8), 256, 0, stream>>>(avw, WoT, h, nullptr, nullptr, nullptr, out);
    ln_k<<<ROWS, 256, 0, stream>>>(out, gamma, beta);
}

// Round 7
// 335.624 us; speedup vs baseline: 1.0820x; 1.0820x over previous
//
#include <hip/hip_runtime.h>
#include <hip/hip_bf16.h>

// MultiHeadAttn: out = LN(h + Attn(h) @ Wo)
// Round 7: GEMM epilogue vectorization via MFMA operand swap (reg-dim = N ->
// u16x4/f32x4 stores), V^T written directly from the QKV epilogue (vtrans_k
// deleted). attn_k / sync structure byte-identical to passing round 6.

typedef __attribute__((ext_vector_type(4))) float f32x4;
typedef __attribute__((ext_vector_type(16))) float f32x16;
typedef __attribute__((ext_vector_type(8))) short s16x8;
typedef unsigned short u16;
typedef unsigned int u32;
typedef __attribute__((ext_vector_type(4))) u16 u16x4;
typedef __attribute__((ext_vector_type(2))) u32 u32x2;

#define SEQ   2048
#define BATCH 4
#define NH    16
#define DH    64
#define DM    1024
#define ROWS  (SEQ*BATCH)   // 8192

// 0.125 (1/sqrt(64)) * log2(e): scores land in log2 domain -> exp2 = 1 VALU op
#define QSCALE 0.18033688011112042f
#define DEFER_THR 11.5416f   // 8 nats in log2 units

__device__ inline u16 f2bf(float x) {
    u32 u = __float_as_uint(x);
    u += 0x7FFF + ((u >> 16) & 1);   // round-to-nearest-even
    return (u16)(u >> 16);
}

__device__ inline u32 cvtpk_bf16(float lo, float hi_) {
    u32 r;
    asm("v_cvt_pk_bf16_f32 %0, %1, %2" : "=v"(r) : "v"(lo), "v"(hi_));
    return r;
}

__device__ inline void gload16(const void* g, void* l) {
    __builtin_amdgcn_global_load_lds((const __attribute__((address_space(1))) void*)g,
                                     (__attribute__((address_space(3))) void*)l, 16, 0, 0);
}

// ---------------- elementwise fp32 -> bf16 ----------------
__global__ __launch_bounds__(256) void conv_f32_bf16(const float* __restrict__ src,
                                                     u16* __restrict__ dst, int n4) {
    int idx = blockIdx.x * 256 + threadIdx.x;
    if (idx >= n4) return;
    f32x4 v = ((const f32x4*)src)[idx];
    u16x4 o;
    #pragma unroll
    for (int j = 0; j < 4; ++j) o[j] = f2bf(v[j]);
    ((u16x4*)dst)[idx] = o;
}

// ---------------- transpose + convert: W [K][N] fp32 -> WT [N][K] bf16 ----------------
__global__ __launch_bounds__(1024) void transconv_k(const float* __restrict__ src,
                                                    u16* __restrict__ dst, int K, int N) {
    __shared__ float t[32][33];
    int tx = threadIdx.x, ty = threadIdx.y;
    int nt = blockIdx.x * 32, kt = blockIdx.y * 32;
    t[ty][tx] = src[(size_t)(kt + ty) * N + nt + tx];
    __syncthreads();
    dst[(size_t)(nt + ty) * K + kt + tx] = f2bf(t[tx][ty]);
}

// ---------------- GEMM: C[M][N] = A[M][K=1024] * BT[N][K]^T ----------------
// round-2 loop structure (128x128 tile, BK=32, dbuf LDS via global_load_lds,
// source-swizzled, plain __syncthreads). MFMA operands SWAPPED: acc =
// mfma(bf, af) so reg-dim = N (4 consecutive cols per thread) -> vector stores.
// MODE 0 (QKV fused, N=3072): col<1024 -> q (scaled); <2048 -> k; else v -> vT direct
// MODE 2: out fp32 = acc + h (residual), f32x4
template<int MODE>
__global__ __launch_bounds__(256) void gemm_k(const u16* __restrict__ A,
                                              const u16* __restrict__ BT,
                                              const float* __restrict__ hres,
                                              u16* __restrict__ o_q,
                                              u16* __restrict__ o_k,
                                              u16* __restrict__ o_v,
                                              float* __restrict__ o_f) {
    __shared__ u16 Al[2][128 * 32];
    __shared__ u16 Bl[2][128 * 32];
    int lane = threadIdx.x & 63, wid = threadIdx.x >> 6;
    int lr = lane & 15, lg = lane >> 4;      // lg in 0..3
    int m0 = blockIdx.x * 128, n0 = blockIdx.y * 128;
    int wr = wid >> 1, wc = wid & 1;

    f32x4 acc[4][4];
    #pragma unroll
    for (int mi = 0; mi < 4; ++mi)
        #pragma unroll
        for (int ni = 0; ni < 4; ++ni)
            #pragma unroll
            for (int rr = 0; rr < 4; ++rr) acc[mi][ni][rr] = 0.f;

#define GEMM_STAGE(bb, kt) do {                                                    \
    int kk = (kt) * 32;                                                            \
    _Pragma("unroll")                                                              \
    for (int it = 0; it < 2; ++it) {                                               \
        int c = (int)threadIdx.x + it * 256;                                       \
        int row = c >> 2, sub = c & 3;                                             \
        int sc = (sub ^ (row & 3)) * 8;                                            \
        gload16(A  + (size_t)(m0 + row) * 1024 + kk + sc,                          \
                &Al[bb][(wid * 64 + it * 256) * 8]);                               \
        gload16(BT + (size_t)(n0 + row) * 1024 + kk + sc,                          \
                &Bl[bb][(wid * 64 + it * 256) * 8]);                               \
    } } while (0)

    GEMM_STAGE(0, 0);
    __syncthreads();
    int cur = 0;
    for (int kt = 0; kt < 32; ++kt) {
        if (kt + 1 < 32) GEMM_STAGE(cur ^ 1, kt + 1);
        const u16* Ab = &Al[cur][0];
        const u16* Bb = &Bl[cur][0];
        s16x8 af[4], bf[4];
        #pragma unroll
        for (int mi = 0; mi < 4; ++mi) {
            int row = wr * 64 + mi * 16 + lr;
            af[mi] = *(const s16x8*)(Ab + row * 32 + ((lg ^ (row & 3)) * 8));
        }
        #pragma unroll
        for (int ni = 0; ni < 4; ++ni) {
            int row = wc * 64 + ni * 16 + lr;
            bf[ni] = *(const s16x8*)(Bb + row * 32 + ((lg ^ (row & 3)) * 8));
        }
        // swapped operands: reg-dim = N (bf), lane-dim = M (af)
        #pragma unroll
        for (int mi = 0; mi < 4; ++mi)
            #pragma unroll
            for (int ni = 0; ni < 4; ++ni)
                acc[mi][ni] = __builtin_amdgcn_mfma_f32_16x16x32_bf16(bf[ni], af[mi], acc[mi][ni], 0, 0, 0);
        __syncthreads();
        cur ^= 1;
    }
#undef GEMM_STAGE

    // epilogue: thread holds rows m = ...+lr ; 4 consecutive cols n = ...+lg*4+e
    #pragma unroll
    for (int mi = 0; mi < 4; ++mi) {
        int row = m0 + wr * 64 + mi * 16 + lr;   // row = i*4 + b
        int ib = row >> 2, bb = row & 3;
        #pragma unroll
        for (int ni = 0; ni < 4; ++ni) {
            int ncol = n0 + wc * 64 + ni * 16 + lg * 4;
            f32x4 v = acc[mi][ni];
            if (MODE == 0) {
                if (ncol < 1024) {
                    int nn = ncol >> 6, dd = ncol & 63;
                    u16x4 o;
                    #pragma unroll
                    for (int e = 0; e < 4; ++e) o[e] = f2bf(v[e] * QSCALE);
                    *(u16x4*)(o_q + (((size_t)(bb * 16 + nn) * SEQ + ib) << 6) + dd) = o;
                } else if (ncol < 2048) {
                    int c2 = ncol - 1024, nn = c2 >> 6, dd = c2 & 63;
                    u16x4 o;
                    #pragma unroll
                    for (int e = 0; e < 4; ++e) o[e] = f2bf(v[e]);
                    *(u16x4*)(o_k + (((size_t)(bb * 16 + nn) * SEQ + ib) << 6) + dd) = o;
                } else {
                    // V^T direct: vT[p][d][j], p=bb*16+nn, d=dd..dd+3, j=ib
                    int c2 = ncol - 2048, nn = c2 >> 6, dd = c2 & 63;
                    size_t base = ((size_t)(bb * 16 + nn) * 64 + dd) * SEQ + ib;
                    #pragma unroll
                    for (int e = 0; e < 4; ++e) o_v[base + (size_t)e * SEQ] = f2bf(v[e]);
                }
            } else {
                size_t off = (size_t)row * 1024 + ncol;
                f32x4 hv = *(const f32x4*)(hres + off);
                *(f32x4*)(o_f + off) = v + hv;
            }
        }
    }
}

// ---------------- flash attention, LDS-staged K/V, swapped-operand 32x32x16 ----------------
// round-2/6 kernel verbatim. grid 1024 x 256; 4 waves/block, 32 q-rows/wave.
__global__ __launch_bounds__(256) void attn_k(const u16* __restrict__ qw, const u16* __restrict__ kw,
                                              const u16* __restrict__ vT, u16* __restrict__ avw) {
    __shared__ u16 Kl[2][64 * 64];
    __shared__ u16 Vl[2][64 * 64];
    int lane = threadIdx.x & 63, wid = threadIdx.x >> 6;
    int l31 = lane & 31, hi = lane >> 5;
    int f = blockIdx.x;
    int pair = (f & 7) * 8 + ((f >> 3) & 7);   // bijective; one pair's 16 blocks -> one XCD
    int qt = f >> 6;
    int b = pair >> 4, n = pair & 15;
    int q0 = qt * 128 + wid * 32;

    const u16* Q  = qw + ((size_t)pair * SEQ + q0) * 64;
    const u16* Kg = kw + (size_t)pair * SEQ * 64;
    const u16* Vg = vT + (size_t)pair * 64 * SEQ;

    // Q B-fragments (held all kernel); qw already scaled by QSCALE (log2 domain)
    s16x8 qf[4];
    #pragma unroll
    for (int kt = 0; kt < 4; ++kt)
        qf[kt] = *(const s16x8*)(Q + (size_t)l31 * 64 + kt * 16 + hi * 8);

    f32x16 Ot[2];   // O^T accum: d = (reg&3)+8*(reg>>2)+4*hi+32*dt, q = l31
    #pragma unroll
    for (int dt = 0; dt < 2; ++dt)
        #pragma unroll
        for (int r = 0; r < 16; ++r) Ot[dt][r] = 0.f;
    float m = -3.0e38f, lsum = 0.f;

#define ATTN_STAGE(bb, j0s) do {                                                   \
    _Pragma("unroll")                                                              \
    for (int it = 0; it < 2; ++it) {                                               \
        int c = (int)threadIdx.x + it * 256;                                       \
        int row = c >> 3, cl = c & 7;                                              \
        int sc = (cl ^ (row & 7)) * 8;                                             \
        gload16(Kg + (size_t)((j0s) + row) * 64 + sc,                              \
                &Kl[bb][(wid * 64 + it * 256) * 8]);                               \
        gload16(Vg + (size_t)row * SEQ + (j0s) + sc,                               \
                &Vl[bb][(wid * 64 + it * 256) * 8]);                               \
    } } while (0)

    ATTN_STAGE(0, 0);
    __syncthreads();
    int cur = 0;

    for (int jt = 0; jt < 32; ++jt) {
        int j0 = jt * 64;
        if (jt + 1 < 32) ATTN_STAGE(cur ^ 1, j0 + 64);
        const u16* Kb = &Kl[cur][0];
        const u16* Vb = &Vl[cur][0];

        // ---- S^T = K Q^T : two 32x32 tiles ----
        f32x16 s0, s1;
        #pragma unroll
        for (int r = 0; r < 16; ++r) { s0[r] = 0.f; s1[r] = 0.f; }
        #pragma unroll
        for (int kt = 0; kt < 4; ++kt) {
            int cg = kt * 2 + hi;
            int r0 = l31;
            s16x8 ka = *(const s16x8*)(Kb + r0 * 64 + ((cg ^ (r0 & 7)) * 8));
            s0 = __builtin_amdgcn_mfma_f32_32x32x16_bf16(ka, qf[kt], s0, 0, 0, 0);
        }
        #pragma unroll
        for (int kt = 0; kt < 4; ++kt) {
            int cg = kt * 2 + hi;
            int r1 = 32 + l31;
            s16x8 ka = *(const s16x8*)(Kb + r1 * 64 + ((cg ^ (r1 & 7)) * 8));
            s1 = __builtin_amdgcn_mfma_f32_32x32x16_bf16(ka, qf[kt], s1, 0, 0, 0);
        }

        // ---- lane-local max over 32 scores ----
        float mx[16];
        #pragma unroll
        for (int r = 0; r < 16; ++r) mx[r] = fmaxf(s0[r], s1[r]);
        #pragma unroll
        for (int st = 8; st >= 1; st >>= 1)
            #pragma unroll
            for (int r = 0; r < st; ++r) mx[r] = fmaxf(mx[r], mx[r + st]);
        float pmax = mx[0];

        // ---- defer-max (T13, log2 units) ----
        if (!__all(pmax - m <= DEFER_THR)) {
            float pmo = fmaxf(pmax, __shfl_xor(pmax, 32, 64));
            float mn = fmaxf(m, pmo);
            float sf = __builtin_amdgcn_exp2f(m - mn);
            m = mn;
            lsum *= sf;
            #pragma unroll
            for (int dt = 0; dt < 2; ++dt)
                #pragma unroll
                for (int r = 0; r < 16; ++r) Ot[dt][r] *= sf;
        }

        // ---- p = exp2(s - m); fp32 sum (4 partials); pack via v_cvt_pk_bf16_f32 ----
        u32 pk[16];
        float ps[4] = {0.f, 0.f, 0.f, 0.f};
        #pragma unroll
        for (int mp = 0; mp < 8; ++mp) {
            float a0 = __builtin_amdgcn_exp2f(s0[2 * mp] - m);
            float a1 = __builtin_amdgcn_exp2f(s0[2 * mp + 1] - m);
            ps[mp & 3] += a0 + a1;
            pk[mp] = cvtpk_bf16(a0, a1);
            float b0 = __builtin_amdgcn_exp2f(s1[2 * mp] - m);
            float b1 = __builtin_amdgcn_exp2f(s1[2 * mp + 1] - m);
            ps[(mp & 3) ^ 2] += b0 + b1;
            pk[8 + mp] = cvtpk_bf16(b0, b1);
        }
        lsum += (ps[0] + ps[1]) + (ps[2] + ps[3]);

        // ---- O^T += V^T P^T ; fragment built by permlane32_swap (2 per 16-slice) ----
        #pragma unroll
        for (int t = 0; t < 2; ++t)
            #pragma unroll
            for (int kt2 = 0; kt2 < 2; ++kt2) {
                int base = t * 8 + kt2 * 4;
                u32x2 w02 = __builtin_amdgcn_permlane32_swap(pk[base + 0], pk[base + 2], false, false);
                u32x2 w13 = __builtin_amdgcn_permlane32_swap(pk[base + 1], pk[base + 3], false, false);
                union { u32 w[4]; s16x8 v; } fr;
                fr.w[0] = w02[0]; fr.w[1] = w13[0]; fr.w[2] = w02[1]; fr.w[3] = w13[1];
                #pragma unroll
                for (int dt = 0; dt < 2; ++dt) {
                    int rv = dt * 32 + l31;
                    int cgv = t * 4 + kt2 * 2 + hi;
                    s16x8 va = *(const s16x8*)(Vb + rv * 64 + ((cgv ^ (rv & 7)) * 8));
                    Ot[dt] = __builtin_amdgcn_mfma_f32_32x32x16_bf16(va, fr.v, Ot[dt], 0, 0, 0);
                }
            }
        __syncthreads();
        cur ^= 1;
    }
#undef ATTN_STAGE

    // ---- epilogue: av[(i*4+b)][n*64+d] = O^T[d][q] / L ----
    float L = lsum + __shfl_xor(lsum, 32, 64);
    float inv = 1.f / L;
    int i = q0 + l31;
    size_t rowo = (size_t)(i * 4 + b) * 1024 + n * 64;
    #pragma unroll
    for (int dt = 0; dt < 2; ++dt)
        #pragma unroll
        for (int rq = 0; rq < 4; ++rq) {
            int dbase = dt * 32 + rq * 8 + hi * 4;
            u16x4 o;
            #pragma unroll
            for (int e = 0; e < 4; ++e) o[e] = f2bf(Ot[dt][rq * 4 + e] * inv);
            *(u16x4*)(avw + rowo + dbase) = o;
        }
}

// ---------------- in-place layernorm over rows of 1024 fp32 ----------------
__global__ __launch_bounds__(256) void ln_k(float* __restrict__ y,
                                            const float* __restrict__ g,
                                            const float* __restrict__ be) {
    int row = blockIdx.x, t = threadIdx.x;
    f32x4 v = ((const f32x4*)(y + (size_t)row * 1024))[t];
    float s = v[0] + v[1] + v[2] + v[3];
    float q = v[0] * v[0] + v[1] * v[1] + v[2] * v[2] + v[3] * v[3];
    #pragma unroll
    for (int msk = 1; msk < 64; msk <<= 1) {
        s += __shfl_xor(s, msk, 64);
        q += __shfl_xor(q, msk, 64);
    }
    __shared__ float ss[4], qq[4];
    int w = t >> 6;
    if ((t & 63) == 0) { ss[w] = s; qq[w] = q; }
    __syncthreads();
    s = ss[0] + ss[1] + ss[2] + ss[3];
    q = qq[0] + qq[1] + qq[2] + qq[3];
    float mean = s * (1.f / 1024.f);
    float var = q * (1.f / 1024.f) - mean * mean;
    float rstd = rsqrtf(var + 1e-5f);
    f32x4 gv = ((const f32x4*)g)[t];
    f32x4 bv = ((const f32x4*)be)[t];
    f32x4 o;
    #pragma unroll
    for (int j = 0; j < 4; ++j) o[j] = (v[j] - mean) * rstd * gv[j] + bv[j];
    ((f32x4*)(y + (size_t)row * 1024))[t] = o;
}

extern "C" void kernel_launch(void* const* d_in, const int* in_sizes, int n_in,
                              void* d_out, int out_size, void* d_ws, size_t ws_size,
                              hipStream_t stream) {
    const float* h     = (const float*)d_in[0];
    const float* Wq    = (const float*)d_in[1];
    const float* Wkv   = (const float*)d_in[2];
    const float* Wo    = (const float*)d_in[3];
    const float* gamma = (const float*)d_in[4];
    const float* beta  = (const float*)d_in[5];
    float* out = (float*)d_out;

    char* w = (char*)d_ws;
    u16* hb   = (u16*)w; w += (size_t)ROWS * DM * 2;        // 16 MB
    u16* WqT  = (u16*)w; w += (size_t)DM * DM * 2;          //  2 MB (WkvT contiguous after)
    u16* WkvT = (u16*)w; w += (size_t)2 * DM * DM * 2;      //  4 MB
    u16* WoT  = (u16*)w; w += (size_t)DM * DM * 2;          //  2 MB
    u16* qw   = (u16*)w; w += (size_t)64 * SEQ * 64 * 2;    // 16 MB
    u16* kw   = (u16*)w; w += (size_t)64 * SEQ * 64 * 2;    // 16 MB
    u16* avw  = (u16*)w; w += (size_t)64 * SEQ * 64 * 2;    // 16 MB
    u16* vT   = (u16*)w; w += (size_t)64 * SEQ * 64 * 2;    // 16 MB

    conv_f32_bf16<<<ROWS * DM / 4 / 256, 256, 0, stream>>>(h, hb, ROWS * DM / 4);
    dim3 b32(32, 32);
    transconv_k<<<dim3(32, 32), b32, 0, stream>>>(Wq, WqT, 1024, 1024);
    transconv_k<<<dim3(64, 32), b32, 0, stream>>>(Wkv, WkvT, 1024, 2048);
    transconv_k<<<dim3(32, 32), b32, 0, stream>>>(Wo, WoT, 1024, 1024);

    // fused QKV projection: BT = [WqT ; WkvT] rows 0..3071; V^T written directly
    gemm_k<0><<<dim3(64, 24), 256, 0, stream>>>(hb, WqT, nullptr, qw, kw, vT, nullptr);
    attn_k<<<1024, 256, 0, stream>>>(qw, kw, vT, avw);
    gemm_k<2><<<dim3(64, 8), 256, 0, stream>>>(avw, WoT, h, nullptr, nullptr, nullptr, out);
    ln_k<<<ROWS, 256, 0, stream>>>(out, gamma, beta);
}